// Round 1
// baseline (709.481 us; speedup 1.0000x reference)
//
#include <hip/hip_runtime.h>

#define NF 29
#define INF 32
#define HD 64
#define NL 7

// ---------------- h0 = concat(x, pos) ----------------
__global__ void build_h0_kernel(const float* __restrict__ x, const float* __restrict__ pos,
                                float* __restrict__ h0, int N) {
    int t = blockIdx.x * blockDim.x + threadIdx.x;
    if (t >= N * INF) return;
    int n = t >> 5, f = t & 31;
    h0[t] = (f < NF) ? x[n * NF + f] : pos[n * 3 + (f - NF)];
}

// ---------------- CSR build ----------------
__global__ void hist_kernel(const int* __restrict__ dst, int E, int* __restrict__ deg) {
    int t = blockIdx.x * blockDim.x + threadIdx.x;
    if (t < E) atomicAdd(&deg[dst[t]], 1);
}

__global__ void scan_kernel(const int* __restrict__ deg, int* __restrict__ rowptr, int N) {
    __shared__ int part[1024];
    int t = threadIdx.x;
    int chunk = (N + 1023) >> 10;
    int lo = t * chunk, hi = min(N, lo + chunk);
    int s = 0;
    for (int i = lo; i < hi; ++i) s += deg[i];
    part[t] = s;
    __syncthreads();
    for (int off = 1; off < 1024; off <<= 1) {
        int v = (t >= off) ? part[t - off] : 0;
        __syncthreads();
        part[t] += v;
        __syncthreads();
    }
    int run = (t == 0) ? 0 : part[t - 1];
    for (int i = lo; i < hi; ++i) { rowptr[i] = run; run += deg[i]; }
    if (t == 1023) rowptr[N] = run;
}

__global__ void copy_int_kernel(const int* __restrict__ a, int* __restrict__ b, int n) {
    int t = blockIdx.x * blockDim.x + threadIdx.x;
    if (t < n) b[t] = a[t];
}

__global__ void scatter_kernel(const int* __restrict__ src, const int* __restrict__ dst, int E,
                               int* __restrict__ cursor, int* __restrict__ colsrc) {
    int t = blockIdx.x * blockDim.x + threadIdx.x;
    if (t < E) {
        int p = atomicAdd(&cursor[dst[t]], 1);
        colsrc[p] = src[t];
    }
}

// ---------------- fused GIN layer: agg + MLP ----------------
// wave-per-node; lane = output feature. Weights staged in LDS.
template<int IN_DIM, bool RELU_OUT>
__global__ __launch_bounds__(256, 4)
void gin_layer_kernel(const float* __restrict__ hin, const int* __restrict__ rowptr,
                      const int* __restrict__ colsrc,
                      const float* __restrict__ Wa, const float* __restrict__ ba,
                      const float* __restrict__ Wb, const float* __restrict__ bb,
                      float* __restrict__ hout, int N)
{
    __shared__ float sWa[IN_DIM * HD];
    __shared__ float sWb[HD * HD];
    __shared__ float sz[4][HD];

    int tid = threadIdx.x;
    for (int i = tid; i < IN_DIM * HD; i += 256) sWa[i] = Wa[i];
    for (int i = tid; i < HD * HD; i += 256) sWb[i] = Wb[i];
    __syncthreads();

    int lane = tid & 63;
    int wv = tid >> 6;
    int flane = lane & (IN_DIM - 1);
    float bav = ba[lane], bbv = bb[lane];

    int gwave = blockIdx.x * 4 + wv;
    int nwaves = gridDim.x * 4;

    for (int node = gwave; node < N; node += nwaves) {
        // self term
        float acc = hin[(size_t)node * IN_DIM + flane];
        int e0 = rowptr[node], e1 = rowptr[node + 1];
        // neighbor aggregation (sum)
        for (int base = e0; base < e1; base += 64) {
            int ec = min(64, e1 - base);
            int sidx = (base + lane < e1) ? colsrc[base + lane] : 0;
            int i = 0;
            for (; i + 3 < ec; i += 4) {
                int s0 = __shfl(sidx, i), s1 = __shfl(sidx, i + 1),
                    s2 = __shfl(sidx, i + 2), s3 = __shfl(sidx, i + 3);
                float v0 = hin[(size_t)s0 * IN_DIM + flane];
                float v1 = hin[(size_t)s1 * IN_DIM + flane];
                float v2 = hin[(size_t)s2 * IN_DIM + flane];
                float v3 = hin[(size_t)s3 * IN_DIM + flane];
                acc += v0 + v1 + v2 + v3;
            }
            for (; i < ec; ++i) {
                int s0 = __shfl(sidx, i);
                acc += hin[(size_t)s0 * IN_DIM + flane];
            }
        }
        // z -> wave-private LDS (same-wave DS ops are in-order; barrier is compiler-only)
        if (lane < IN_DIM) sz[wv][lane] = acc;
        __builtin_amdgcn_wave_barrier();
        float t1 = 0.f;
        #pragma unroll
        for (int k = 0; k < IN_DIM; ++k) t1 = fmaf(sz[wv][k], sWa[k * HD + lane], t1);
        t1 += bav;
        t1 = fmaxf(t1, 0.f);
        __builtin_amdgcn_wave_barrier();
        sz[wv][lane] = t1;
        __builtin_amdgcn_wave_barrier();
        float o = 0.f;
        #pragma unroll
        for (int k = 0; k < HD; ++k) o = fmaf(sz[wv][k], sWb[k * HD + lane], o);
        o += bbv;
        if (RELU_OUT) o = fmaxf(o, 0.f);
        hout[(size_t)node * HD + lane] = o;
    }
}

// ---------------- global mean pool (stage 1: partial sums) ----------------
__global__ void pool_kernel(const float* __restrict__ h, const int* __restrict__ batch,
                            float* __restrict__ pool, float* __restrict__ cnt, int N) {
    int lane = threadIdx.x;  // 64 threads
    int nblk = gridDim.x;
    int per = (N + nblk - 1) / nblk;
    int lo = blockIdx.x * per, hi = min(N, lo + per);
    if (lo >= hi) return;
    int cur = batch[lo];
    float acc = 0.f, c = 0.f;
    for (int n = lo; n < hi; ++n) {
        int b = batch[n];
        if (b != cur) {
            atomicAdd(&pool[cur * HD + lane], acc);
            if (lane == 0) atomicAdd(&cnt[cur], c);
            acc = 0.f; c = 0.f; cur = b;
        }
        acc += h[(size_t)n * HD + lane];
        c += 1.f;
    }
    atomicAdd(&pool[cur * HD + lane], acc);
    if (lane == 0) atomicAdd(&cnt[cur], c);
}

// ---------------- mean + linear head ----------------
__global__ void final_kernel(const float* __restrict__ pool, const float* __restrict__ cnt,
                             const float* __restrict__ lin_w, const float* __restrict__ lin_b,
                             float* __restrict__ out, int B) {
    int b = blockIdx.x;
    int lane = threadIdx.x;
    float c = fmaxf(cnt[b], 1.f);
    float v = pool[b * HD + lane] / c * lin_w[lane];
    for (int off = 32; off > 0; off >>= 1) v += __shfl_down(v, off);
    if (lane == 0) out[b] = v + lin_b[0];
}

extern "C" void kernel_launch(void* const* d_in, const int* in_sizes, int n_in,
                              void* d_out, int out_size, void* d_ws, size_t ws_size,
                              hipStream_t stream)
{
    const float* x   = (const float*)d_in[0];
    const float* pos = (const float*)d_in[1];
    const int*  eidx = (const int*)d_in[2];
    const int* batch = (const int*)d_in[3];
    const float* W1f = (const float*)d_in[4];
    const float* W1r = (const float*)d_in[5];
    const float* b1  = (const float*)d_in[6];
    const float* W2  = (const float*)d_in[7];
    const float* b2  = (const float*)d_in[8];
    const float* lw  = (const float*)d_in[9];
    const float* lb  = (const float*)d_in[10];

    int N = in_sizes[3];
    int E = in_sizes[2] / 2;
    int B = out_size;
    const int* src = eidx;
    const int* dst = eidx + E;

    char* ws = (char*)d_ws;
    size_t off = 0;
    auto alloc = [&](size_t bytes) -> void* {
        void* p = ws + off;
        off += (bytes + 255) & ~(size_t)255;
        return p;
    };
    float* bufA   = (float*)alloc((size_t)N * HD * 4);
    float* bufB   = (float*)alloc((size_t)N * HD * 4);
    int*   rowptr = (int*)  alloc((size_t)(N + 1) * 4);
    int*   cursor = (int*)  alloc((size_t)N * 4);
    int*   colsrc = (int*)  alloc((size_t)E * 4);
    float* pool   = (float*)alloc((size_t)B * HD * 4);
    float* cnt    = (float*)alloc((size_t)B * 4);

    hipMemsetAsync(cursor, 0, (size_t)N * 4, stream);
    hipMemsetAsync(pool, 0, (size_t)B * HD * 4, stream);
    hipMemsetAsync(cnt, 0, (size_t)B * 4, stream);

    build_h0_kernel<<<(N * INF + 255) / 256, 256, 0, stream>>>(x, pos, bufA, N);
    hist_kernel<<<(E + 255) / 256, 256, 0, stream>>>(dst, E, cursor);
    scan_kernel<<<1, 1024, 0, stream>>>(cursor, rowptr, N);
    copy_int_kernel<<<(N + 255) / 256, 256, 0, stream>>>(rowptr, cursor, N);
    scatter_kernel<<<(E + 255) / 256, 256, 0, stream>>>(src, dst, E, cursor, colsrc);

    const int grid = 1024;
    // layer 0: IN=32, outer relu
    gin_layer_kernel<INF, true><<<grid, 256, 0, stream>>>(bufA, rowptr, colsrc,
                                                          W1f, b1, W2, b2, bufB, N);
    float* cur_in = bufB;
    float* cur_out = bufA;
    for (int l = 1; l < NL; ++l) {
        const float* Wa = W1r + (size_t)(l - 1) * HD * HD;
        const float* ba = b1 + l * HD;
        const float* Wb = W2 + (size_t)l * HD * HD;
        const float* bb = b2 + l * HD;
        if (l < NL - 1)
            gin_layer_kernel<HD, true><<<grid, 256, 0, stream>>>(cur_in, rowptr, colsrc,
                                                                 Wa, ba, Wb, bb, cur_out, N);
        else
            gin_layer_kernel<HD, false><<<grid, 256, 0, stream>>>(cur_in, rowptr, colsrc,
                                                                  Wa, ba, Wb, bb, cur_out, N);
        float* tmp = cur_in; cur_in = cur_out; cur_out = tmp;
    }
    // result now in cur_in
    pool_kernel<<<512, 64, 0, stream>>>(cur_in, batch, pool, cnt, N);
    final_kernel<<<B, 64, 0, stream>>>(pool, cnt, lw, lb, (float*)d_out, B);
}